// Round 15
// baseline (684.886 us; speedup 1.0000x reference)
//
#include <hip/hip_runtime.h>
#include <stdint.h>

typedef __bf16 bf16x8 __attribute__((ext_vector_type(8)));
typedef float f32x4 __attribute__((ext_vector_type(4)));
typedef unsigned short ushort8 __attribute__((ext_vector_type(8)));

__device__ __forceinline__ float bf2f(unsigned short u) {
  union { uint32_t i; float f; } v; v.i = ((uint32_t)u) << 16; return v.f;
}
__device__ __forceinline__ unsigned short f2bf(float f) {
  union { uint32_t i; float f; } v; v.f = f;
  uint32_t u = v.i;
  return (unsigned short)((u + 0x7fffu + ((u >> 16) & 1u)) >> 16);
}
__device__ __forceinline__ float sigm(float x) { return 1.0f / (1.0f + __expf(-x)); }
__device__ __forceinline__ float tanh_f(float x) { return 1.0f - 2.0f / (__expf(2.0f * x) + 1.0f); }

__device__ __forceinline__ ushort4 cvt4(float4 a) {
  ushort4 o; o.x = f2bf(a.x); o.y = f2bf(a.y); o.z = f2bf(a.z); o.w = f2bf(a.w); return o;
}

// bijective XCD-aware remap (m204)
__device__ __forceinline__ int xcd_swz(int bid, int nwg) {
  int q = nwg >> 3, r = nwg & 7;
  int x = bid & 7, idx = bid >> 3;
  return (x < r ? x * (q + 1) : r * (q + 1) + (x - r) * q) + idx;
}

// ---------- fp32 -> bf16 bulk convert (weights) ----------
__global__ void k_f2bf(const float* __restrict__ src, unsigned short* __restrict__ dst, long long n8) {
  long long t = (long long)blockIdx.x * blockDim.x + threadIdx.x;
  if (t >= n8) return;
  const float4* s = (const float4*)src + t * 2;
  float4 a = s[0], b = s[1];
  ((ushort4*)dst)[t * 2]     = cvt4(a);
  ((ushort4*)dst)[t * 2 + 1] = cvt4(b);
}

// ---------- merged histograms: parent->deg, child->chdeg ----------
__global__ void k_hist2(const int* __restrict__ parent, const int* __restrict__ child,
                        int* __restrict__ deg, int* __restrict__ chdeg, int M) {
  int e = blockIdx.x * blockDim.x + threadIdx.x;
  if (e >= M) return;
  atomicAdd(&deg[parent[e]], 1);
  atomicAdd(&chdeg[child[e]], 1);
}

// ---------- packed scan pass 1: 3 fields of 21 bits ----------
__global__ void k_scan1(const int* __restrict__ deg, const int* __restrict__ chdeg,
                        unsigned long long* __restrict__ ps,
                        unsigned long long* __restrict__ bsum, int Nn) {
  __shared__ unsigned long long tmp[256];
  int t = blockIdx.x * 256 + threadIdx.x;
  int d  = (t < Nn) ? deg[t] : 0;
  int cf = (t < Nn && chdeg[t] > 0) ? 1 : 0;
  unsigned long long v = (unsigned long long)(unsigned)d
                       | ((d > 0) ? (1ull << 21) : 0ull)
                       | ((unsigned long long)cf << 42);
  tmp[threadIdx.x] = v;
  __syncthreads();
#pragma unroll
  for (int s = 1; s < 256; s <<= 1) {
    unsigned long long a = (threadIdx.x >= (unsigned)s) ? tmp[threadIdx.x - s] : 0;
    __syncthreads();
    tmp[threadIdx.x] += a;
    __syncthreads();
  }
  if (t < Nn) ps[t] = tmp[threadIdx.x] - v;
  if (threadIdx.x == 255) bsum[blockIdx.x] = tmp[255];
}

// ---------- scan pass 2 + meta: Ni, L0 (256-aligned), leaf-limit, Mc ----------
__global__ void k_scan2(unsigned long long* __restrict__ bsum, int nb,
                        int* __restrict__ meta, int Nn) {
  __shared__ unsigned long long tmp[512];
  int i = threadIdx.x;
  unsigned long long v = (i < nb) ? bsum[i] : 0;
  tmp[i] = v;
  __syncthreads();
#pragma unroll
  for (int s = 1; s < 512; s <<= 1) {
    unsigned long long a = (i >= s) ? tmp[i - s] : 0;
    __syncthreads();
    tmp[i] += a;
    __syncthreads();
  }
  if (i < nb) bsum[i] = tmp[i] - v;
  if (i == 511) {
    int Ni = (int)((tmp[511] >> 21) & 0x1FFFFF);
    int L0 = ((Ni + 255) >> 8) << 8;
    meta[0] = Ni;
    meta[1] = L0;
    meta[2] = L0 + (Nn - Ni);
    meta[3] = (int)((tmp[511] >> 42) & 0x1FFFFF);   // Mc
  }
}

// ---------- scan pass 3: rs/cursor + slot/nodeof + cidx/cnodes ----------
__global__ void k_scan3(const unsigned long long* __restrict__ ps,
                        const unsigned long long* __restrict__ bsum,
                        const int* __restrict__ meta, const int* __restrict__ deg,
                        const int* __restrict__ chdeg,
                        int* __restrict__ rs, int* __restrict__ cursor,
                        int* __restrict__ slot, int* __restrict__ nodeof,
                        int* __restrict__ cidx, int* __restrict__ cnodes, int Nn) {
  int t = blockIdx.x * 256 + threadIdx.x;
  if (t >= Nn) return;
  unsigned long long p = ps[t] + bsum[blockIdx.x];
  int r  = (int)(p & 0x1FFFFF);
  int si = (int)((p >> 21) & 0x1FFFFF);
  int ci = (int)((p >> 42) & 0x1FFFFF);
  rs[t] = r;
  cursor[t] = r;
  int sl = (deg[t] > 0) ? si : (meta[1] + (t - si));
  slot[t] = sl;
  nodeof[sl] = t;
  cidx[t] = ci;
  if (chdeg[t] > 0) cnodes[ci] = t;
}

// ---------- bucket edges by parent; store COMPACT child row ----------
__global__ void k_fill(const int* __restrict__ parent, const int* __restrict__ child,
                       const int* __restrict__ cidx,
                       int* __restrict__ cursor, int* __restrict__ childlist, int M) {
  int e = blockIdx.x * blockDim.x + threadIdx.x;
  if (e >= M) return;
  int p = parent[e];
  int pos = atomicAdd(&cursor[p], 1);
  childlist[pos] = cidx[child[e]];
}

// ---------- compact h -> bf16 into hf[cidx][0..511] ----------
__global__ void k_h2bf_compact(const float* __restrict__ h, const int* __restrict__ chdeg,
                               const int* __restrict__ cidx,
                               unsigned short* __restrict__ hf, int Nn) {
  long long t = (long long)blockIdx.x * blockDim.x + threadIdx.x;
  int n = (int)(t >> 6);
  if (n >= Nn) return;
  if (chdeg[n] == 0) return;
  int j = ((int)t & 63) * 8;
  const float4* s = (const float4*)(h + (size_t)n * 512 + j);
  size_t d = (size_t)cidx[n] * 1024 + j;
  ((ushort4*)(hf + d))[0] = cvt4(s[0]);
  ((ushort4*)(hf + d))[1] = cvt4(s[1]);
}

// ---------- gather-reduce: one 2KB interleaved row per child ----------
__global__ void k_reduce(const unsigned short* __restrict__ hf, const float* __restrict__ x,
                         const int* __restrict__ rs, const int* __restrict__ childlist,
                         const int* __restrict__ slot,
                         unsigned short* __restrict__ Zp, unsigned short* __restrict__ credb,
                         int Nn, int M) {
  int p = blockIdx.x * 4 + (threadIdx.x >> 6);
  if (p >= Nn) return;
  int ln = threadIdx.x & 63;
  int j = ln * 8;
  int start = rs[p];
  int end = (p + 1 < Nn) ? rs[p + 1] : M;
  size_t zb = (size_t)slot[p] * 512 + j;
  if (end > start) {
    float hs[8] = {0, 0, 0, 0, 0, 0, 0, 0};
    float cs[8] = {0, 0, 0, 0, 0, 0, 0, 0};
    int ri = childlist[start];
    for (int i = start; i < end; ++i) {
      int rin = (i + 1 < end) ? childlist[i + 1] : ri;   // prefetch next index
      size_t cb = (size_t)ri * 1024 + j;
      ushort8 hv = *(const ushort8*)(hf + cb);
      ushort8 fv = *(const ushort8*)(hf + cb + 512);
#pragma unroll
      for (int q = 0; q < 8; ++q) {
        hs[q] += bf2f(hv[q]);
        cs[q] += bf2f(fv[q]);
      }
      ri = rin;
    }
    float4 h0 = {hs[0], hs[1], hs[2], hs[3]}, h1 = {hs[4], hs[5], hs[6], hs[7]};
    float4 c0 = {cs[0], cs[1], cs[2], cs[3]}, c1 = {cs[4], cs[5], cs[6], cs[7]};
    ((ushort4*)(Zp + zb))[0] = cvt4(h0);
    ((ushort4*)(Zp + zb))[1] = cvt4(h1);
    size_t cr = (size_t)p * 512 + j;
    ((ushort4*)(credb + cr))[0] = cvt4(c0);
    ((ushort4*)(credb + cr))[1] = cvt4(c1);
  } else {
    const float4* s = (const float4*)(x + (size_t)p * 512 + j);
    float4 x0 = s[0], x1 = s[1];
    ((ushort4*)(Zp + zb))[0] = cvt4(x0);
    ((ushort4*)(Zp + zb))[1] = cvt4(x1);
  }
}

// ---------- f-gate GEMM (compact rows, stride-1024 A): fc-half of hf = sigmoid(h @ Wf^T + b) * c[node] ----------
__global__ __launch_bounds__(512)
void k_gemm_f(unsigned short* __restrict__ hf,
              const unsigned short* __restrict__ Bt,
              const float* __restrict__ bias, const float* __restrict__ cmat,
              const int* __restrict__ meta, const int* __restrict__ cnodes) {
  __shared__ __align__(16) unsigned short ldsA[2][256 * 32];
  __shared__ __align__(16) unsigned short ldsB[2][128 * 32];
  const int K = 512;
  const int tid = threadIdx.x;
  const int wv = tid >> 6, ln = tid & 63;
  const int wr = wv >> 1, wc = wv & 1;
  int wg = xcd_swz(blockIdx.x, gridDim.x);
  int rowp = wg >> 2;
  int colp = wg & 3;
  const int row0 = rowp * 256;
  const int col0 = colp * 128;
  const int Mc = meta[3];
  if (row0 >= Mc) return;

  f32x4 acc[4][4] = {};

  auto stage = [&](int buf, int k0) {
#pragma unroll
    for (int rep = 0; rep < 2; ++rep) {
      int cidx2 = rep * 512 + tid;
      int r  = cidx2 >> 2;
      int kc = cidx2 & 3;
      int kp = (kc ^ ((r >> 1) & 3)) * 8;
      int ga = row0 + r; if (ga > Mc - 1) ga = Mc - 1;
      const unsigned short* srcA = hf + (size_t)ga * 1024 + k0 + kp;
      __builtin_amdgcn_global_load_lds(
          (const __attribute__((address_space(1))) void*)(void*)srcA,
          (__attribute__((address_space(3))) void*)(&ldsA[buf][(size_t)cidx2 * 8]),
          16, 0, 0);
    }
    {
      int cidx2 = tid;
      int r  = cidx2 >> 2;
      int kc = cidx2 & 3;
      int kp = (kc ^ ((r >> 1) & 3)) * 8;
      const unsigned short* srcB = Bt + (size_t)(col0 + r) * K + k0 + kp;
      __builtin_amdgcn_global_load_lds(
          (const __attribute__((address_space(1))) void*)(void*)srcB,
          (__attribute__((address_space(3))) void*)(&ldsB[buf][(size_t)cidx2 * 8]),
          16, 0, 0);
    }
  };

  const int kcr = ((ln >> 4) ^ ((ln >> 1) & 3)) * 8;
  auto compute = [&](int buf) {
    bf16x8 af[4], bfr[4];
#pragma unroll
    for (int mi = 0; mi < 4; ++mi)
      af[mi] = *(const bf16x8*)(&ldsA[buf][(size_t)(wr * 64 + mi * 16 + (ln & 15)) * 32 + kcr]);
#pragma unroll
    for (int ni = 0; ni < 4; ++ni)
      bfr[ni] = *(const bf16x8*)(&ldsB[buf][(size_t)(wc * 64 + ni * 16 + (ln & 15)) * 32 + kcr]);
#pragma unroll
    for (int mi = 0; mi < 4; ++mi)
#pragma unroll
      for (int ni = 0; ni < 4; ++ni)
        acc[mi][ni] = __builtin_amdgcn_mfma_f32_16x16x32_bf16(bfr[ni], af[mi], acc[mi][ni], 0, 0, 0);
  };

  stage(0, 0);
  int cur = 0;
#pragma unroll
  for (int kt = 0; kt < 15; ++kt) {
    stage(cur ^ 1, (kt + 1) * 32);
    asm volatile("s_waitcnt vmcnt(3)" ::: "memory");
    __builtin_amdgcn_s_barrier();
    compute(cur);
    __builtin_amdgcn_s_barrier();
    cur ^= 1;
  }
  asm volatile("s_waitcnt vmcnt(0)" ::: "memory");
  __builtin_amdgcn_s_barrier();
  compute(cur);

#pragma unroll
  for (int mi = 0; mi < 4; ++mi) {
    int gm = row0 + wr * 64 + mi * 16 + (ln & 15);
    if (gm >= Mc) continue;
    int node = cnodes[gm];
#pragma unroll
    for (int ni = 0; ni < 4; ++ni) {
      int gn = col0 + wc * 64 + ni * 16 + (ln >> 4) * 4;
      float4 bv = *(const float4*)(bias + gn);
      float4 cv = *(const float4*)(cmat + (size_t)node * 512 + gn);
      ushort4 o;
      o.x = f2bf(sigm(acc[mi][ni][0] + bv.x) * cv.x);
      o.y = f2bf(sigm(acc[mi][ni][1] + bv.y) * cv.y);
      o.z = f2bf(sigm(acc[mi][ni][2] + bv.z) * cv.z);
      o.w = f2bf(sigm(acc[mi][ni][3] + bv.w) * cv.w);
      *(ushort4*)(hf + (size_t)gm * 1024 + 512 + gn) = o;
    }
  }
}

// ---------- iou GEMM: 256x128, 8 waves, counted-vmcnt dbuf pipeline + T2 swizzle ----------
__global__ __launch_bounds__(512)
void k_gemm_iou(const unsigned short* __restrict__ Zp,
                const unsigned short* __restrict__ Ub,
                const unsigned short* __restrict__ Wb,
                const float* __restrict__ bias,
                const int* __restrict__ meta,
                const int* __restrict__ nodeof,
                unsigned short* __restrict__ C) {
  __shared__ __align__(16) unsigned short ldsA[2][256 * 32];
  __shared__ __align__(16) unsigned short ldsB[2][128 * 32];
  const int K = 512, ldc = 1536;
  const int tid = threadIdx.x;
  const int wv = tid >> 6, ln = tid & 63;
  const int wr = wv >> 1, wc = wv & 1;
  int wg = xcd_swz(blockIdx.x, gridDim.x);
  int rowp = wg / 12;
  int colp = wg - rowp * 12;
  const int row0 = rowp * 256;
  const int col0 = colp * 128;

  const int Ni = meta[0], L0 = meta[1], lim2 = meta[2];
  const bool internal = row0 < L0;
  const int limit = internal ? Ni : lim2;
  if (row0 >= limit) return;
  const unsigned short* __restrict__ Bt = internal ? Ub : Wb;

  f32x4 acc[4][4] = {};

  auto stage = [&](int buf, int k0) {
#pragma unroll
    for (int rep = 0; rep < 2; ++rep) {
      int cidx2 = rep * 512 + tid;
      int r  = cidx2 >> 2;
      int kc = cidx2 & 3;
      int kp = (kc ^ ((r >> 1) & 3)) * 8;
      int ga = row0 + r; if (ga > limit - 1) ga = limit - 1;
      const unsigned short* srcA = Zp + (size_t)ga * K + k0 + kp;
      __builtin_amdgcn_global_load_lds(
          (const __attribute__((address_space(1))) void*)(void*)srcA,
          (__attribute__((address_space(3))) void*)(&ldsA[buf][(size_t)cidx2 * 8]),
          16, 0, 0);
    }
    {
      int cidx2 = tid;
      int r  = cidx2 >> 2;
      int kc = cidx2 & 3;
      int kp = (kc ^ ((r >> 1) & 3)) * 8;
      const unsigned short* srcB = Bt + (size_t)(col0 + r) * K + k0 + kp;
      __builtin_amdgcn_global_load_lds(
          (const __attribute__((address_space(1))) void*)(void*)srcB,
          (__attribute__((address_space(3))) void*)(&ldsB[buf][(size_t)cidx2 * 8]),
          16, 0, 0);
    }
  };

  const int kcr = ((ln >> 4) ^ ((ln >> 1) & 3)) * 8;
  auto compute = [&](int buf) {
    bf16x8 af[4], bfr[4];
#pragma unroll
    for (int mi = 0; mi < 4; ++mi)
      af[mi] = *(const bf16x8*)(&ldsA[buf][(size_t)(wr * 64 + mi * 16 + (ln & 15)) * 32 + kcr]);
#pragma unroll
    for (int ni = 0; ni < 4; ++ni)
      bfr[ni] = *(const bf16x8*)(&ldsB[buf][(size_t)(wc * 64 + ni * 16 + (ln & 15)) * 32 + kcr]);
#pragma unroll
    for (int mi = 0; mi < 4; ++mi)
#pragma unroll
      for (int ni = 0; ni < 4; ++ni)
        acc[mi][ni] = __builtin_amdgcn_mfma_f32_16x16x32_bf16(bfr[ni], af[mi], acc[mi][ni], 0, 0, 0);
  };

  stage(0, 0);
  int cur = 0;
#pragma unroll
  for (int kt = 0; kt < 15; ++kt) {
    stage(cur ^ 1, (kt + 1) * 32);
    asm volatile("s_waitcnt vmcnt(3)" ::: "memory");
    __builtin_amdgcn_s_barrier();
    compute(cur);
    __builtin_amdgcn_s_barrier();
    cur ^= 1;
  }
  asm volatile("s_waitcnt vmcnt(0)" ::: "memory");
  __builtin_amdgcn_s_barrier();
  compute(cur);

#pragma unroll
  for (int mi = 0; mi < 4; ++mi) {
    int m = row0 + wr * 64 + mi * 16 + (ln & 15);
    if (m >= limit) continue;
    int node = nodeof[m];
    size_t ob = (size_t)node * ldc;
#pragma unroll
    for (int ni = 0; ni < 4; ++ni) {
      int gn = col0 + wc * 64 + ni * 16 + (ln >> 4) * 4;
      float4 bv = *(const float4*)(bias + gn);
      ushort4 o;
      o.x = f2bf(acc[mi][ni][0] + bv.x);
      o.y = f2bf(acc[mi][ni][1] + bv.y);
      o.z = f2bf(acc[mi][ni][2] + bv.z);
      o.w = f2bf(acc[mi][ni][3] + bv.w);
      *(ushort4*)(C + ob + gn) = o;
    }
  }
}

// ---------- LSTM epilogue: fully coalesced (node-order iou + credb) ----------
__global__ void k_epilogue(const unsigned short* __restrict__ iou,
                           const unsigned short* __restrict__ credb,
                           const int* __restrict__ deg,
                           float* __restrict__ out, int Nn) {
  long long t = (long long)blockIdx.x * blockDim.x + threadIdx.x;
  int n = (int)(t >> 6);
  if (n >= Nn) return;
  int j = ((int)t & 63) * 8;
  size_t ib = (size_t)n * 1536;
  ushort4 iv0 = *(const ushort4*)(iou + ib + j);
  ushort4 iv1 = *(const ushort4*)(iou + ib + j + 4);
  ushort4 ov0 = *(const ushort4*)(iou + ib + 512 + j);
  ushort4 ov1 = *(const ushort4*)(iou + ib + 512 + j + 4);
  ushort4 uv0 = *(const ushort4*)(iou + ib + 1024 + j);
  ushort4 uv1 = *(const ushort4*)(iou + ib + 1024 + j + 4);

  float carr[8] = {0, 0, 0, 0, 0, 0, 0, 0};
  if (deg[n] > 0) {
    size_t cr = (size_t)n * 512 + j;
    ushort4 c0 = *(const ushort4*)(credb + cr);
    ushort4 c1 = *(const ushort4*)(credb + cr + 4);
    carr[0] = bf2f(c0.x); carr[1] = bf2f(c0.y); carr[2] = bf2f(c0.z); carr[3] = bf2f(c0.w);
    carr[4] = bf2f(c1.x); carr[5] = bf2f(c1.y); carr[6] = bf2f(c1.z); carr[7] = bf2f(c1.w);
  }

  float iarr[8] = {bf2f(iv0.x), bf2f(iv0.y), bf2f(iv0.z), bf2f(iv0.w),
                   bf2f(iv1.x), bf2f(iv1.y), bf2f(iv1.z), bf2f(iv1.w)};
  float oarr[8] = {bf2f(ov0.x), bf2f(ov0.y), bf2f(ov0.z), bf2f(ov0.w),
                   bf2f(ov1.x), bf2f(ov1.y), bf2f(ov1.z), bf2f(ov1.w)};
  float uarr[8] = {bf2f(uv0.x), bf2f(uv0.y), bf2f(uv0.z), bf2f(uv0.w),
                   bf2f(uv1.x), bf2f(uv1.y), bf2f(uv1.z), bf2f(uv1.w)};
  float hn[8], cn[8];
#pragma unroll
  for (int q = 0; q < 8; ++q) {
    float cc = sigm(iarr[q]) * tanh_f(uarr[q]) + carr[q];
    cn[q] = cc;
    hn[q] = sigm(oarr[q]) * tanh_f(cc);
  }
  size_t hb = (size_t)n * 512 + j;
  size_t cb = (size_t)Nn * 512 + hb;
  *(float4*)(out + hb)     = make_float4(hn[0], hn[1], hn[2], hn[3]);
  *(float4*)(out + hb + 4) = make_float4(hn[4], hn[5], hn[6], hn[7]);
  *(float4*)(out + cb)     = make_float4(cn[0], cn[1], cn[2], cn[3]);
  *(float4*)(out + cb + 4) = make_float4(cn[4], cn[5], cn[6], cn[7]);
}

extern "C" void kernel_launch(void* const* d_in, const int* in_sizes, int n_in,
                              void* d_out, int out_size, void* d_ws, size_t ws_size,
                              hipStream_t stream) {
  const float* x     = (const float*)d_in[0];
  const float* h     = (const float*)d_in[1];
  const float* c     = (const float*)d_in[2];
  const int* child   = (const int*)d_in[3];
  const int* parent  = (const int*)d_in[4];
  const float* W_iou = (const float*)d_in[5];
  const float* U_iou = (const float*)d_in[6];
  const float* b_iou = (const float*)d_in[7];
  const float* U_f_w = (const float*)d_in[8];
  const float* U_f_b = (const float*)d_in[9];

  const int Nn = in_sizes[0] / 512;   // 100000
  const int M  = in_sizes[3];         // 99999

  float* out = (float*)d_out;

  // ---- workspace arena ----
  char* ws = (char*)d_ws;
  auto al = [](size_t v) { return (v + 255) & ~(size_t)255; };
  size_t sz0    = al((size_t)Nn * 1536 * 2);          // iou (node-order)
  size_t offZp  = sz0;
  size_t szZp   = al((size_t)(Nn + 256) * 512 * 2);   // Zp by slot
  size_t offHf  = offZp + szZp;
  size_t szHf   = al((size_t)(Nn + 256) * 1024 * 2);  // hf: interleaved h|fc compact rows
  size_t offCr  = offHf + szHf;
  size_t szCr   = al((size_t)Nn * 512 * 2);           // credb node-order
  size_t offDeg = offCr + szCr;
  size_t szN4   = al((size_t)Nn * 4);
  size_t offChd = offDeg + szN4;
  size_t offRs  = offChd + szN4;
  size_t offCur = offRs + szN4;
  size_t offSl  = offCur + szN4;
  size_t offNo  = offSl + szN4;
  size_t szNo   = al((size_t)(Nn + 256) * 4);
  size_t offCi  = offNo + szNo;
  size_t offCn  = offCi + szN4;
  size_t offPs  = offCn + szN4;
  size_t szPs   = al((size_t)Nn * 8);
  size_t offCl  = offPs + szPs;
  size_t szCl   = al((size_t)M * 4);
  size_t offBs  = offCl + szCl;
  size_t szBs   = al(512 * 8);
  size_t offMt  = offBs + szBs;
  size_t szMt   = 256;
  size_t offWf  = offMt + szMt;
  size_t szWf   = al(512 * 512 * 2);
  size_t offUb  = offWf + szWf;
  size_t szUw   = al((size_t)1536 * 512 * 2);
  size_t offWb  = offUb + szUw;
  size_t needed = offWb + szUw;
  if (ws_size < needed) return;

  unsigned short* iou   = (unsigned short*)(ws);
  unsigned short* Zp    = (unsigned short*)(ws + offZp);
  unsigned short* hf    = (unsigned short*)(ws + offHf);
  unsigned short* credb = (unsigned short*)(ws + offCr);
  int*            deg   = (int*)(ws + offDeg);
  int*            chdeg = (int*)(ws + offChd);
  int*            rs    = (int*)(ws + offRs);
  int*            cursor= (int*)(ws + offCur);
  int*            slot  = (int*)(ws + offSl);
  int*            nodeof= (int*)(ws + offNo);
  int*            cidx  = (int*)(ws + offCi);
  int*            cnodes= (int*)(ws + offCn);
  unsigned long long* ps   = (unsigned long long*)(ws + offPs);
  int*            clist = (int*)(ws + offCl);
  unsigned long long* bsum = (unsigned long long*)(ws + offBs);
  int*            meta  = (int*)(ws + offMt);
  unsigned short* Wf    = (unsigned short*)(ws + offWf);
  unsigned short* Ub    = (unsigned short*)(ws + offUb);
  unsigned short* Wb    = (unsigned short*)(ws + offWb);

  hipMemsetAsync(deg, 0, 2 * szN4, stream);   // deg + chdeg

  // 1. weight conversions
  k_f2bf<<<(512 * 512 / 8 + 255) / 256, 256, 0, stream>>>(U_f_w, Wf, 512 * 512 / 8);
  k_f2bf<<<(1536 * 512 / 8 + 255) / 256, 256, 0, stream>>>(U_iou, Ub, 1536 * 512 / 8);
  k_f2bf<<<(1536 * 512 / 8 + 255) / 256, 256, 0, stream>>>(W_iou, Wb, 1536 * 512 / 8);

  // 2. CSR + partition + compaction build (one packed 3-field scan)
  int nb1 = (Nn + 255) / 256;
  k_hist2<<<(M + 255) / 256, 256, 0, stream>>>(parent, child, deg, chdeg, M);
  k_scan1<<<nb1, 256, 0, stream>>>(deg, chdeg, ps, bsum, Nn);
  k_scan2<<<1, 512, 0, stream>>>(bsum, nb1, meta, Nn);
  k_scan3<<<nb1, 256, 0, stream>>>(ps, bsum, meta, deg, chdeg, rs, cursor, slot, nodeof, cidx, cnodes, Nn);
  k_fill<<<(M + 255) / 256, 256, 0, stream>>>(parent, child, cidx, cursor, clist, M);

  // 3. compact h -> bf16 into hf (h-half)
  k_h2bf_compact<<<(int)(((long long)Nn * 64 + 255) / 256), 256, 0, stream>>>(h, chdeg, cidx, hf, Nn);

  // 4. hf fc-half = sigmoid(hf h-half @ Wf^T + U_f_b) * c[node]
  int nbyF = (Nn + 255) / 256;   // upper bound; blocks past Mc exit
  k_gemm_f<<<nbyF * 4, 512, 0, stream>>>(hf, Wf, U_f_b, c, meta, cnodes);

  // 5. gather-reduce -> Zp (slot-order), credb (node-order)
  k_reduce<<<(Nn + 3) / 4, 256, 0, stream>>>(hf, x, rs, clist, slot, Zp, credb, Nn, M);

  // 6. iou[node] = Zp @ (U_iou|W_iou)^T + b_iou  (K=512, round-9 pipeline)
  int nbyI = (Nn >> 8) + 2;
  k_gemm_iou<<<nbyI * 12, 512, 0, stream>>>(Zp, Ub, Wb, b_iou, meta, nodeof, iou);

  // 7. epilogue -> h_new, c_new (fully coalesced)
  k_epilogue<<<(int)(((long long)Nn * 64 + 255) / 256), 256, 0, stream>>>(iou, credb, deg, out, Nn);
}